// Round 22
// baseline (43.999 us; speedup 1.0000x reference)
//
#include <hip/hip_runtime.h>
#include <math.h>

// NonlocalWeightedAverage via MX-scaled fp8 MFMA (K=64), fixed-reference
// softmax. corr[m,n] = <lf_m, lf_n>, lf = 3x3-unfolded feature, K = 9*64.
// R22: R21 (8 barrier periods, 10-slot ring/zh, A-hoist, no spill) + three
// scheduling micro-levers: (1) s_setprio(1) around each sub-SP's load+MFMA
// cluster (T5: waves drift between roles within a period -> scheduler can
// favor compute waves); (2) first MFMA consumes a loop-invariant zero vector
// (compile-time ternary) -> acc-zero movs DCE'd; (3) prefetch split 2+2
// around the first sub-SP so VMEM issue spreads across the period.

#define B_ 4
#define CH 64
#define H_ 64
#define W_ 64
#define SCALE2 14.426950408889634f   // (1/ALPHA=10) * log2(e)
#define STRIPE 1056                  // 66 xx * 16 B
#define ROWB (4 * STRIPE)            // 4224 B: one feature row (fp8)
#define NRING 10

typedef __attribute__((ext_vector_type(4)))  unsigned int uint4v;
typedef __attribute__((ext_vector_type(16))) float f32x16;
typedef __attribute__((ext_vector_type(8)))  int int8v;

__device__ inline void glds16(const void* g, void* l) {
    __builtin_amdgcn_global_load_lds(
        (const __attribute__((address_space(1))) unsigned int*)g,
        (__attribute__((address_space(3))) unsigned int*)l, 16, 0, 0);
}

// decode OCP e4m3fn (NaN never occurs for our data: |f| <= ~5 << 448)
__device__ inline float dec_e4m3(unsigned u) {
    unsigned e = (u >> 3) & 15u, m = u & 7u;
    float v = e ? __uint_as_float(((e + 120u) << 23) | (m << 20))
                : (float)m * 0x1p-9f;
    return (u & 0x80u) ? -v : v;
}

// feat [B,C,H,W] f32 -> tf [B,H,W,64] fp8 e4m3 (fragment-pair packed), plus
// per-pixel channel-norm^2 of the DECODED fp8 values -> n2 [B,H,W].
__global__ __launch_bounds__(256) void feat_to_fp8(
    const float* __restrict__ feat, unsigned char* __restrict__ tf,
    float* __restrict__ n2)
{
    const int b = blockIdx.y, y = blockIdx.x, t = (int)threadIdx.x;
    __shared__ float ld[CH][W_ + 1];
    #pragma unroll
    for (int i = 0; i < 16; ++i) {
        int idx = i * 256 + t;
        int c = idx >> 6, x = idx & 63;
        ld[c][x] = feat[(((size_t)b * CH + c) * H_ + y) * W_ + x];
    }
    __syncthreads();
    const int x = t >> 2, g = t & 3;
    const int cbase = (g >> 1) * 32 + (g & 1) * 8;
    unsigned int wd[4];
    #pragma unroll
    for (int w4 = 0; w4 < 4; ++w4) {
        float f[4];
        #pragma unroll
        for (int e = 0; e < 4; ++e) {
            int j = w4 * 4 + e;
            f[e] = ld[cbase + ((j >> 3) << 4) + (j & 7)][x];
        }
        unsigned int wv = 0;
        wv = __builtin_amdgcn_cvt_pk_fp8_f32(f[0], f[1], wv, false);
        wv = __builtin_amdgcn_cvt_pk_fp8_f32(f[2], f[3], wv, true);
        wd[w4] = wv;
    }
    float s = 0.f;
    #pragma unroll
    for (int w4 = 0; w4 < 4; ++w4)
        #pragma unroll
        for (int e = 0; e < 4; ++e) {
            float d = dec_e4m3((wd[w4] >> (8 * e)) & 0xffu);
            s = fmaf(d, d, s);
        }
    s += __shfl_xor(s, 1);
    s += __shfl_xor(s, 2);
    if (g == 0) n2[((size_t)b * H_ + y) * W_ + x] = s;

    unsigned char* dst = tf + (((size_t)b * H_ + y) * W_ + x) * CH + g * 16;
    *(uint4v*)dst = (uint4v){wd[0], wd[1], wd[2], wd[3]};
}

#define MXMFMA(A, Bv, C) \
    __builtin_amdgcn_mfma_scale_f32_32x32x64_f8f6f4(A, Bv, C, 0, 0, 0, 0x7F, 0, 0x7F)

// One 2-gen sub-superphase at base row YB (gens YB, YB+1).
#define SUBSP(YB)                                                              \
  {                                                                            \
    const int yb = (YB);                                                       \
    f32x16 acc0 = Z, acc1 = Z;                                                 \
    const char* rb[4];                                                         \
    _Pragma("unroll")                                                          \
    for (int j2 = 0; j2 < 4; ++j2)                                             \
        rb[j2] = ring + ((yb + j2) % NRING) * ROWB;                            \
    __builtin_amdgcn_s_setprio(1);                                             \
    _Pragma("unroll")                                                          \
    for (int dx = 0; dx < 3; ++dx) {                                           \
        const int ob = (xn + dx) * 16;                                         \
        int8v Bb0 = ld32(rb[0], ob);                                           \
        int8v Bb1 = ld32(rb[1], ob);                                           \
        int8v Bb2 = ld32(rb[2], ob);                                           \
        int8v Bb3 = ld32(rb[3], ob);                                           \
        acc0 = MXMFMA(Areg0[dx], Bb0, dx == 0 ? Z : acc0);                     \
        acc0 = MXMFMA(Areg1[dx], Bb1, acc0);                                   \
        acc0 = MXMFMA(Areg2[dx], Bb2, acc0);                                   \
        acc1 = MXMFMA(Areg0[dx], Bb1, dx == 0 ? Z : acc1);                     \
        acc1 = MXMFMA(Areg1[dx], Bb2, acc1);                                   \
        acc1 = MXMFMA(Areg2[dx], Bb3, acc1);                                   \
    }                                                                          \
    __builtin_amdgcn_s_setprio(0);                                             \
    _Pragma("unroll")                                                          \
    for (int j = 0; j < 2; ++j) {                                              \
        const f32x16& ac = (j == 0) ? acc0 : acc1;                             \
        float v[16]; int upd = 0;                                              \
        _Pragma("unroll")                                                      \
        for (int r = 0; r < 16; ++r) {                                         \
            v[r] = fmaf(ac[r], SCALE2, -Mref[r]);                              \
            upd |= (v[r] > -30.0f) ? 1 : 0;                                    \
        }                                                                      \
        if (__any(upd)) {                                                      \
            const int yn = yb + j;                                             \
            float av = aab[yn * W_ + xn];                                      \
            float bv = bab[yn * W_ + xn];                                      \
            _Pragma("unroll")                                                  \
            for (int r = 0; r < 16; ++r) {                                     \
                float pp  = exp2f(fminf(v[r], 80.0f));                         \
                float w0c = pp * av;                                           \
                float w1c = pp * bv;                                           \
                _Pragma("unroll")                                              \
                for (int off = 16; off >= 1; off >>= 1) {                      \
                    pp  += __shfl_xor(pp,  off);                               \
                    w0c += __shfl_xor(w0c, off);                               \
                    w1c += __shfl_xor(w1c, off);                               \
                }                                                              \
                if (l31 == 0) {                                                \
                    int m = (mt << 5) + (r & 3) + ((r >> 2) << 3) + (h << 2);  \
                    float* st = &state[zh][nh][m][0];                          \
                    st[0] += pp; st[1] += w0c; st[2] += w1c;                   \
                }                                                              \
            }                                                                  \
        }                                                                      \
    }                                                                          \
  }

__global__ __launch_bounds__(512) void nlwa_fp8(
    const float* __restrict__ xlab,
    const unsigned char* __restrict__ tf,
    const float* __restrict__ n2,
    float* __restrict__ out)
{
    const int b = blockIdx.y, ym = blockIdx.x;
    const int tid = (int)threadIdx.x;
    const int w = tid >> 6, l = tid & 63;   // EIGHT waves
    const int l31 = l & 31, h = l >> 5;
    const int zh = w >> 2;            // yn-half: [0,32) or [32,64)
    const int w4 = w & 3;             // wave-in-half
    const int mt = (w >> 1) & 1, nh = w & 1;
    const int lo = zh << 5;

    __shared__ __attribute__((aligned(16))) char smem[23 * ROWB]; // 2x10 ring + 3 A
    __shared__ float state[2][2][64][4];  // [zh][nh][m]{S,W0,W1,pad}
    __shared__ float mref_lds[64];
    char* ring  = smem + zh * (NRING * ROWB);
    char* aslab = smem + 2 * NRING * ROWB;

    const unsigned char* tfb = tf + (size_t)b * H_ * W_ * CH;
    const float* aab = xlab + ((size_t)b * 3 + 1) * H_ * W_;
    const float* bab = xlab + ((size_t)b * 3 + 2) * H_ * W_;

    // zero pad columns xx=0,65: 23 slabs x 4 stripes x 2 = 184 16B-chunks
    if (tid < 184) {
        int s23 = tid >> 3, rem = tid & 7;
        int which = rem >> 2, t = rem & 3;
        char* base = smem + s23 * ROWB;
        *(uint4v*)(base + t * STRIPE + (which ? 65 * 16 : 0)) = (uint4v){0,0,0,0};
    }
    // zero softmax state (1024 floats over 512 threads)
    #pragma unroll
    for (int i = 0; i < 2; ++i) ((float*)state)[i * 512 + tid] = 0.f;

    // Mref[x] = SCALE2 * 3x3 box-sum of n2 around (ym, x), zero-padded
    if (tid < 64) {
        const float* n2b = n2 + (size_t)b * H_ * W_;
        float s = 0.f;
        #pragma unroll
        for (int dy = -1; dy <= 1; ++dy) {
            int y = ym + dy;
            if ((unsigned)y < H_) {
                #pragma unroll
                for (int dx = -1; dx <= 1; ++dx) {
                    int x = tid + dx;
                    if ((unsigned)x < W_) s += n2b[y * W_ + x];
                }
            }
        }
        mref_lds[tid] = s * SCALE2;
    }

    // stage one (row y, stripe t): async DMA into xx=1..64 (1024 B), or zeros
    auto stage = [&](char* slabBase, int y, int t) {
        char* dst = slabBase + t * STRIPE + 16;
        if ((unsigned)y < H_) {
            const unsigned char* gp = tfb + ((size_t)y * W_ + l) * CH + t * 16;
            glds16(gp, dst);
        } else {
            *(uint4v*)(dst + l * 16) = (uint4v){0, 0, 0, 0};
        }
    };

    // prologue (R18's verified map). zh0: ring rows lo-1..lo+4 (24 tasks) +
    // A rows ym-1..ym+1 (12 tasks) = 36. zh1: ring rows lo-1..lo+4 (24).
    if (zh == 0) {
        for (int tau = w4; tau < 36; tau += 4) {
            int r = tau >> 2, t = tau & 3;
            if (r < 6) {
                int y = lo - 1 + r;
                stage(ring + ((y + 1) % NRING) * ROWB, y, t);
            } else {
                int dy = r - 6;
                stage(aslab + dy * ROWB, ym + dy - 1, t);
            }
        }
    } else {
        for (int tau = w4; tau < 24; tau += 4) {
            int r = tau >> 2, t = tau & 3;
            int y = lo - 1 + r;
            stage(ring + ((y + 1) % NRING) * ROWB, y, t);
        }
    }

    const int xn = (nh << 5) + l31;   // lane's n-column
    const int xm = (mt << 5) + l31;   // lane's m-position (A-side)
    const int soL = h * STRIPE;       // stripe g = h     (qq=0 half)
    const int soH = (2 + h) * STRIPE; // stripe g = 2 + h (qq=1 half)

    // 32B MX operand: stripe pair {h, 2+h} at pixel offset -> v8i32
    auto ld32 = [&](const char* slab, int off) -> int8v {
        uint4v r0 = *(const uint4v*)(slab + soL + off);
        uint4v r1 = *(const uint4v*)(slab + soH + off);
        int8v a;
        a[0] = r0[0]; a[1] = r0[1]; a[2] = r0[2]; a[3] = r0[3];
        a[4] = r1[0]; a[5] = r1[1]; a[6] = r1[2]; a[7] = r1[3];
        return a;
    };

    __syncthreads();   // prologue DMAs drained (incl. aslab)

    // ---- A-fragments hoisted to registers: loop-invariant, 9 x int8v ----
    int8v Areg0[3], Areg1[3], Areg2[3];   // [dyi] x [dx], statically unrolled
    #pragma unroll
    for (int dx = 0; dx < 3; ++dx) {
        const int oa = (xm + dx) * 16;
        Areg0[dx] = ld32(aslab + 0 * ROWB, oa);
        Areg1[dx] = ld32(aslab + 1 * ROWB, oa);
        Areg2[dx] = ld32(aslab + 2 * ROWB, oa);
    }

    float Mref[16];
    #pragma unroll
    for (int r = 0; r < 16; ++r)
        Mref[r] = mref_lds[(mt << 5) + (r & 3) + ((r >> 2) << 3) + (h << 2)];

    // loop-invariant zero accumulator (first MFMA of each acc consumes it)
    f32x16 Z;
    #pragma unroll
    for (int r = 0; r < 16; ++r) Z[r] = 0.f;

    // 8 barrier periods; each = split prefetch + TWO 2-gen sub-superphases.
    #pragma unroll 1
    for (int p = 0; p < 8; ++p) {
        const int y0 = lo + (p << 2);
        const bool pf = (p < 7);

        // prefetch rows y0+5,y0+6 -> slots (y0+6,y0+7)%10 (disjoint from
        // working slots (y0..y0+5)%10). Wave w4 stages stripe w4.
        if (pf) {
            stage(ring + ((y0 + 6) % NRING) * ROWB, y0 + 5, w4);
            stage(ring + ((y0 + 7) % NRING) * ROWB, y0 + 6, w4);
        }

        SUBSP(y0)

        // prefetch rows y0+7,y0+8 -> slots (y0+8,y0+9)%10
        if (pf) {
            stage(ring + ((y0 + 8) % NRING) * ROWB, y0 + 7, w4);
            stage(ring + ((y0 + 9) % NRING) * ROWB, y0 + 8, w4);
        }

        SUBSP(y0 + 2)

        __syncthreads();   // period DMAs drained; slots rotate; state visible
    }

    // final: sum the 4 partial states, write output directly
    if (tid < 64) {
        float Ssum = 0.f, w0 = 0.f, w1 = 0.f;
        #pragma unroll
        for (int z2 = 0; z2 < 2; ++z2)
            #pragma unroll
            for (int n2i = 0; n2i < 2; ++n2i) {
                Ssum += state[z2][n2i][tid][0];
                w0   += state[z2][n2i][tid][1];
                w1   += state[z2][n2i][tid][2];
            }
        float inv = 1.0f / Ssum;
        out[(((size_t)b * 2 + 0) * H_ + ym) * W_ + tid] = w0 * inv;
        out[(((size_t)b * 2 + 1) * H_ + ym) * W_ + tid] = w1 * inv;
    }
}

extern "C" void kernel_launch(void* const* d_in, const int* in_sizes, int n_in,
                              void* d_out, int out_size, void* d_ws, size_t ws_size,
                              hipStream_t stream) {
    const float* xlab = (const float*)d_in[0];
    const float* feat = (const float*)d_in[1];
    float* out = (float*)d_out;
    unsigned char* tf = (unsigned char*)d_ws;                          // 1 MB
    float* n2   = (float*)((char*)d_ws + (size_t)1024 * 1024);         // 64 KB

    dim3 gridT(H_, B_);
    feat_to_fp8<<<gridT, 256, 0, stream>>>(feat, tf, n2);
    dim3 gridM(H_, B_);
    nlwa_fp8<<<gridM, 512, 0, stream>>>(xlab, tf, n2, out);
}

// Round 23
// 43.207 us; speedup vs baseline: 1.0183x; 1.0183x over previous
//
#include <hip/hip_runtime.h>
#include <math.h>

// NonlocalWeightedAverage via MX-scaled fp8 MFMA (K=64), fixed-reference
// softmax. corr[m,n] = <lf_m, lf_n>, lf = 3x3-unfolded feature, K = 9*64.
// R23: R21 + B-operand CARRY across sub-superphases. Consecutive 2-gen
// sub-SPs share 2 of 4 B-rows; ping-pong named pairs (BP/BQ, static parity
// per period position -> zero reg moves) halve steady-state B LDS reads
// (24 -> 12 b128/sub-SP). LDS pipe ~37K -> ~21K cyc/CU, under the MFMA term.
// Carries persist through barriers; prefetch-slot disjointness unchanged
// (reads use slots (y0..y0+5)%10, prefetch writes (y0+6..y0+9)%10).
// Telltale: WRITE_SIZE MBs = allocator spilled the carry -> revert.

#define B_ 4
#define CH 64
#define H_ 64
#define W_ 64
#define SCALE2 14.426950408889634f   // (1/ALPHA=10) * log2(e)
#define STRIPE 1056                  // 66 xx * 16 B
#define ROWB (4 * STRIPE)            // 4224 B: one feature row (fp8)
#define NRING 10

typedef __attribute__((ext_vector_type(4)))  unsigned int uint4v;
typedef __attribute__((ext_vector_type(16))) float f32x16;
typedef __attribute__((ext_vector_type(8)))  int int8v;

__device__ inline void glds16(const void* g, void* l) {
    __builtin_amdgcn_global_load_lds(
        (const __attribute__((address_space(1))) unsigned int*)g,
        (__attribute__((address_space(3))) unsigned int*)l, 16, 0, 0);
}

// decode OCP e4m3fn (NaN never occurs for our data: |f| <= ~5 << 448)
__device__ inline float dec_e4m3(unsigned u) {
    unsigned e = (u >> 3) & 15u, m = u & 7u;
    float v = e ? __uint_as_float(((e + 120u) << 23) | (m << 20))
                : (float)m * 0x1p-9f;
    return (u & 0x80u) ? -v : v;
}

// feat [B,C,H,W] f32 -> tf [B,H,W,64] fp8 e4m3 (fragment-pair packed), plus
// per-pixel channel-norm^2 of the DECODED fp8 values -> n2 [B,H,W].
__global__ __launch_bounds__(256) void feat_to_fp8(
    const float* __restrict__ feat, unsigned char* __restrict__ tf,
    float* __restrict__ n2)
{
    const int b = blockIdx.y, y = blockIdx.x, t = (int)threadIdx.x;
    __shared__ float ld[CH][W_ + 1];
    #pragma unroll
    for (int i = 0; i < 16; ++i) {
        int idx = i * 256 + t;
        int c = idx >> 6, x = idx & 63;
        ld[c][x] = feat[(((size_t)b * CH + c) * H_ + y) * W_ + x];
    }
    __syncthreads();
    const int x = t >> 2, g = t & 3;
    const int cbase = (g >> 1) * 32 + (g & 1) * 8;
    unsigned int wd[4];
    #pragma unroll
    for (int w4 = 0; w4 < 4; ++w4) {
        float f[4];
        #pragma unroll
        for (int e = 0; e < 4; ++e) {
            int j = w4 * 4 + e;
            f[e] = ld[cbase + ((j >> 3) << 4) + (j & 7)][x];
        }
        unsigned int wv = 0;
        wv = __builtin_amdgcn_cvt_pk_fp8_f32(f[0], f[1], wv, false);
        wv = __builtin_amdgcn_cvt_pk_fp8_f32(f[2], f[3], wv, true);
        wd[w4] = wv;
    }
    float s = 0.f;
    #pragma unroll
    for (int w4 = 0; w4 < 4; ++w4)
        #pragma unroll
        for (int e = 0; e < 4; ++e) {
            float d = dec_e4m3((wd[w4] >> (8 * e)) & 0xffu);
            s = fmaf(d, d, s);
        }
    s += __shfl_xor(s, 1);
    s += __shfl_xor(s, 2);
    if (g == 0) n2[((size_t)b * H_ + y) * W_ + x] = s;

    unsigned char* dst = tf + (((size_t)b * H_ + y) * W_ + x) * CH + g * 16;
    *(uint4v*)dst = (uint4v){wd[0], wd[1], wd[2], wd[3]};
}

#define MXMFMA(A, Bv, C) \
    __builtin_amdgcn_mfma_scale_f32_32x32x64_f8f6f4(A, Bv, C, 0, 0, 0, 0x7F, 0, 0x7F)

// One 2-gen sub-superphase at base row YB (gens YB, YB+1).
// B rows: yb-1=OLD0, yb=OLD1 (carried unless LOADOLD), yb+1=NEW0, yb+2=NEW1
// (loaded here, carried into the next sub-SP as its OLD pair).
#define SUBSP(YB, OLD0, OLD1, NEW0, NEW1, LOADOLD)                             \
  {                                                                            \
    const int yb = (YB);                                                       \
    const char* rs0 = ring + ((yb    ) % NRING) * ROWB;                        \
    const char* rs1 = ring + ((yb + 1) % NRING) * ROWB;                        \
    const char* rs2 = ring + ((yb + 2) % NRING) * ROWB;                        \
    const char* rs3 = ring + ((yb + 3) % NRING) * ROWB;                        \
    f32x16 acc0, acc1;                                                         \
    _Pragma("unroll")                                                          \
    for (int r = 0; r < 16; ++r) { acc0[r] = 0.f; acc1[r] = 0.f; }             \
    _Pragma("unroll")                                                          \
    for (int dx = 0; dx < 3; ++dx) {                                           \
        const int ob = (xn + dx) * 16;                                         \
        if (LOADOLD) {                                                         \
            OLD0[dx] = ld32(rs0, ob);                                          \
            OLD1[dx] = ld32(rs1, ob);                                          \
        }                                                                      \
        NEW0[dx] = ld32(rs2, ob);                                              \
        NEW1[dx] = ld32(rs3, ob);                                              \
        acc0 = MXMFMA(Areg0[dx], OLD0[dx], acc0);                              \
        acc0 = MXMFMA(Areg1[dx], OLD1[dx], acc0);                              \
        acc0 = MXMFMA(Areg2[dx], NEW0[dx], acc0);                              \
        acc1 = MXMFMA(Areg0[dx], OLD1[dx], acc1);                              \
        acc1 = MXMFMA(Areg1[dx], NEW0[dx], acc1);                              \
        acc1 = MXMFMA(Areg2[dx], NEW1[dx], acc1);                              \
    }                                                                          \
    _Pragma("unroll")                                                          \
    for (int j = 0; j < 2; ++j) {                                              \
        const f32x16& ac = (j == 0) ? acc0 : acc1;                             \
        float v[16]; int upd = 0;                                              \
        _Pragma("unroll")                                                      \
        for (int r = 0; r < 16; ++r) {                                         \
            v[r] = fmaf(ac[r], SCALE2, -Mref[r]);                              \
            upd |= (v[r] > -30.0f) ? 1 : 0;                                    \
        }                                                                      \
        if (__any(upd)) {                                                      \
            const int yn = yb + j;                                             \
            float av = aab[yn * W_ + xn];                                      \
            float bv = bab[yn * W_ + xn];                                      \
            _Pragma("unroll")                                                  \
            for (int r = 0; r < 16; ++r) {                                     \
                float pp  = exp2f(fminf(v[r], 80.0f));                         \
                float w0c = pp * av;                                           \
                float w1c = pp * bv;                                           \
                _Pragma("unroll")                                              \
                for (int off = 16; off >= 1; off >>= 1) {                      \
                    pp  += __shfl_xor(pp,  off);                               \
                    w0c += __shfl_xor(w0c, off);                               \
                    w1c += __shfl_xor(w1c, off);                               \
                }                                                              \
                if (l31 == 0) {                                                \
                    int m = (mt << 5) + (r & 3) + ((r >> 2) << 3) + (h << 2);  \
                    float* st = &state[zh][nh][m][0];                          \
                    st[0] += pp; st[1] += w0c; st[2] += w1c;                   \
                }                                                              \
            }                                                                  \
        }                                                                      \
    }                                                                          \
  }

__global__ __launch_bounds__(512) void nlwa_fp8(
    const float* __restrict__ xlab,
    const unsigned char* __restrict__ tf,
    const float* __restrict__ n2,
    float* __restrict__ out)
{
    const int b = blockIdx.y, ym = blockIdx.x;
    const int tid = (int)threadIdx.x;
    const int w = tid >> 6, l = tid & 63;   // EIGHT waves
    const int l31 = l & 31, h = l >> 5;
    const int zh = w >> 2;            // yn-half: [0,32) or [32,64)
    const int w4 = w & 3;             // wave-in-half
    const int mt = (w >> 1) & 1, nh = w & 1;
    const int lo = zh << 5;

    __shared__ __attribute__((aligned(16))) char smem[23 * ROWB]; // 2x10 ring + 3 A
    __shared__ float state[2][2][64][4];  // [zh][nh][m]{S,W0,W1,pad}
    __shared__ float mref_lds[64];
    char* ring  = smem + zh * (NRING * ROWB);
    char* aslab = smem + 2 * NRING * ROWB;

    const unsigned char* tfb = tf + (size_t)b * H_ * W_ * CH;
    const float* aab = xlab + ((size_t)b * 3 + 1) * H_ * W_;
    const float* bab = xlab + ((size_t)b * 3 + 2) * H_ * W_;

    // zero pad columns xx=0,65: 23 slabs x 4 stripes x 2 = 184 16B-chunks
    if (tid < 184) {
        int s23 = tid >> 3, rem = tid & 7;
        int which = rem >> 2, t = rem & 3;
        char* base = smem + s23 * ROWB;
        *(uint4v*)(base + t * STRIPE + (which ? 65 * 16 : 0)) = (uint4v){0,0,0,0};
    }
    // zero softmax state (1024 floats over 512 threads)
    #pragma unroll
    for (int i = 0; i < 2; ++i) ((float*)state)[i * 512 + tid] = 0.f;

    // Mref[x] = SCALE2 * 3x3 box-sum of n2 around (ym, x), zero-padded
    if (tid < 64) {
        const float* n2b = n2 + (size_t)b * H_ * W_;
        float s = 0.f;
        #pragma unroll
        for (int dy = -1; dy <= 1; ++dy) {
            int y = ym + dy;
            if ((unsigned)y < H_) {
                #pragma unroll
                for (int dx = -1; dx <= 1; ++dx) {
                    int x = tid + dx;
                    if ((unsigned)x < W_) s += n2b[y * W_ + x];
                }
            }
        }
        mref_lds[tid] = s * SCALE2;
    }

    // stage one (row y, stripe t): async DMA into xx=1..64 (1024 B), or zeros
    auto stage = [&](char* slabBase, int y, int t) {
        char* dst = slabBase + t * STRIPE + 16;
        if ((unsigned)y < H_) {
            const unsigned char* gp = tfb + ((size_t)y * W_ + l) * CH + t * 16;
            glds16(gp, dst);
        } else {
            *(uint4v*)(dst + l * 16) = (uint4v){0, 0, 0, 0};
        }
    };

    // prologue (R18's verified map). zh0: ring rows lo-1..lo+4 (24 tasks) +
    // A rows ym-1..ym+1 (12 tasks) = 36. zh1: ring rows lo-1..lo+4 (24).
    if (zh == 0) {
        for (int tau = w4; tau < 36; tau += 4) {
            int r = tau >> 2, t = tau & 3;
            if (r < 6) {
                int y = lo - 1 + r;
                stage(ring + ((y + 1) % NRING) * ROWB, y, t);
            } else {
                int dy = r - 6;
                stage(aslab + dy * ROWB, ym + dy - 1, t);
            }
        }
    } else {
        for (int tau = w4; tau < 24; tau += 4) {
            int r = tau >> 2, t = tau & 3;
            int y = lo - 1 + r;
            stage(ring + ((y + 1) % NRING) * ROWB, y, t);
        }
    }

    const int xn = (nh << 5) + l31;   // lane's n-column
    const int xm = (mt << 5) + l31;   // lane's m-position (A-side)
    const int soL = h * STRIPE;       // stripe g = h     (qq=0 half)
    const int soH = (2 + h) * STRIPE; // stripe g = 2 + h (qq=1 half)

    // 32B MX operand: stripe pair {h, 2+h} at pixel offset -> v8i32
    auto ld32 = [&](const char* slab, int off) -> int8v {
        uint4v r0 = *(const uint4v*)(slab + soL + off);
        uint4v r1 = *(const uint4v*)(slab + soH + off);
        int8v a;
        a[0] = r0[0]; a[1] = r0[1]; a[2] = r0[2]; a[3] = r0[3];
        a[4] = r1[0]; a[5] = r1[1]; a[6] = r1[2]; a[7] = r1[3];
        return a;
    };

    __syncthreads();   // prologue DMAs drained (incl. aslab)

    // ---- A-fragments hoisted to registers: loop-invariant, 9 x int8v ----
    int8v Areg0[3], Areg1[3], Areg2[3];   // [dyi] x [dx], statically unrolled
    #pragma unroll
    for (int dx = 0; dx < 3; ++dx) {
        const int oa = (xm + dx) * 16;
        Areg0[dx] = ld32(aslab + 0 * ROWB, oa);
        Areg1[dx] = ld32(aslab + 1 * ROWB, oa);
        Areg2[dx] = ld32(aslab + 2 * ROWB, oa);
    }

    float Mref[16];
    #pragma unroll
    for (int r = 0; r < 16; ++r)
        Mref[r] = mref_lds[(mt << 5) + (r & 3) + ((r >> 2) << 3) + (h << 2)];

    // B-operand ping-pong pairs: even sub-SP consumes BP, loads BQ; odd
    // consumes BQ, loads BP. Statically indexed (unrolled dx) -> registers.
    int8v BP0[3], BP1[3], BQ0[3], BQ1[3];

    // ---- period 0 (peeled: first sub-SP loads its OLD pair) ----
    {
        const int y0 = lo;
        #pragma unroll
        for (int k = 0; k < 4; ++k) {
            int y = y0 + 5 + k;
            stage(ring + ((y + 1) % NRING) * ROWB, y, w4);
        }
        SUBSP(y0,     BP0, BP1, BQ0, BQ1, 1)
        SUBSP(y0 + 2, BQ0, BQ1, BP0, BP1, 0)
        __syncthreads();
    }

    // ---- periods 1..7: carry-only (6 ld32 per sub-SP) ----
    #pragma unroll 1
    for (int p = 1; p < 8; ++p) {
        const int y0 = lo + (p << 2);

        // prefetch rows y0+5..y0+8 -> slots (y0+6..y0+9)%10, disjoint from
        // read slots (y0..y0+5)%10. Wave w4 stages stripe w4 of each row.
        if (p < 7) {
            #pragma unroll
            for (int k = 0; k < 4; ++k) {
                int y = y0 + 5 + k;
                stage(ring + ((y + 1) % NRING) * ROWB, y, w4);
            }
        }

        SUBSP(y0,     BP0, BP1, BQ0, BQ1, 0)
        SUBSP(y0 + 2, BQ0, BQ1, BP0, BP1, 0)

        __syncthreads();   // period DMAs drained; slots rotate; state visible
    }

    // final: sum the 4 partial states, write output directly
    if (tid < 64) {
        float Ssum = 0.f, w0 = 0.f, w1 = 0.f;
        #pragma unroll
        for (int z2 = 0; z2 < 2; ++z2)
            #pragma unroll
            for (int n2i = 0; n2i < 2; ++n2i) {
                Ssum += state[z2][n2i][tid][0];
                w0   += state[z2][n2i][tid][1];
                w1   += state[z2][n2i][tid][2];
            }
        float inv = 1.0f / Ssum;
        out[(((size_t)b * 2 + 0) * H_ + ym) * W_ + tid] = w0 * inv;
        out[(((size_t)b * 2 + 1) * H_ + ym) * W_ + tid] = w1 * inv;
    }
}

extern "C" void kernel_launch(void* const* d_in, const int* in_sizes, int n_in,
                              void* d_out, int out_size, void* d_ws, size_t ws_size,
                              hipStream_t stream) {
    const float* xlab = (const float*)d_in[0];
    const float* feat = (const float*)d_in[1];
    float* out = (float*)d_out;
    unsigned char* tf = (unsigned char*)d_ws;                          // 1 MB
    float* n2   = (float*)((char*)d_ws + (size_t)1024 * 1024);         // 64 KB

    dim3 gridT(H_, B_);
    feat_to_fp8<<<gridT, 256, 0, stream>>>(feat, tf, n2);
    dim3 gridM(H_, B_);
    nlwa_fp8<<<gridM, 512, 0, stream>>>(xlab, tf, n2, out);
}